// Round 7
// baseline (99.750 us; speedup 1.0000x reference)
//
#include <hip/hip_runtime.h>
#include <hip/hip_bf16.h>

#define N_NODES 8192
#define F_IN 256
#define F_OUT 128

#define SPLITK 4
#define KQ (N_NODES / SPLITK)   // 2048
#define BK 32
#define NT (KQ / BK)            // 64
#define ABYTES 8192             // A tile: 64 rows x 32 k x fp32 (128 B/row)
#define BBYTES 8192             // B tile: 128 f x 32 k x bf16  (64 B/row)
#define BUFB (ABYTES + BBYTES)  // 16 KB
#define NBUF 4                  // 64 KB total

typedef __attribute__((ext_vector_type(4))) float f32x4;
typedef __attribute__((ext_vector_type(8))) short bf16x8;

static __device__ __forceinline__ short bfr(float x) {
    __hip_bfloat16 h = __float2bfloat16(x);   // RNE
    union { __hip_bfloat16 h; short s; } u; u.h = h;
    return u.s;
}

static __device__ __forceinline__ void gload16(const void* g, void* l) {
    __builtin_amdgcn_global_load_lds(
        (const __attribute__((address_space(1))) unsigned int*)g,
        (__attribute__((address_space(3))) unsigned int*)l, 16, 0, 0);
}

// Kernel 1: support^T[f][n] = sum_k X[n][k] * W[k][f]   (fp32 accum -> bf16)
__global__ __launch_bounds__(256) void support_kernel(
        const float* __restrict__ X, const float* __restrict__ W,
        unsigned short* __restrict__ supT) {
    __shared__ float Xs[32][68];
    __shared__ float Ws[64][128];
    const int t = threadIdx.x;
    const int n0 = blockIdx.x * 32;
    const int tc = t & 31;
    const int tr = t >> 5;
    float acc[4][4];
    #pragma unroll
    for (int i = 0; i < 4; ++i)
        #pragma unroll
        for (int j = 0; j < 4; ++j) acc[i][j] = 0.f;

    for (int k0 = 0; k0 < F_IN; k0 += 64) {
        __syncthreads();
        {
            const int r = t >> 3, kc = (t & 7) * 8;
            const float* src = X + (size_t)(n0 + r) * F_IN + k0 + kc;
            f32x4 v0 = *(const f32x4*)src;
            f32x4 v1 = *(const f32x4*)(src + 4);
            *(f32x4*)&Xs[r][kc]     = v0;
            *(f32x4*)&Xs[r][kc + 4] = v1;
        }
        {
            const int col = t & 127, kb = t >> 7;
            #pragma unroll
            for (int i = 0; i < 32; ++i) {
                const int k = kb + i * 2;
                Ws[k][col] = W[(size_t)(k0 + k) * F_OUT + col];
            }
        }
        __syncthreads();
        #pragma unroll 8
        for (int k = 0; k < 64; ++k) {
            const f32x4 b = *(const f32x4*)&Ws[k][tc * 4];
            float a[4];
            #pragma unroll
            for (int i = 0; i < 4; ++i) a[i] = Xs[tr * 4 + i][k];
            #pragma unroll
            for (int i = 0; i < 4; ++i) {
                acc[i][0] += a[i] * b.x; acc[i][1] += a[i] * b.y;
                acc[i][2] += a[i] * b.z; acc[i][3] += a[i] * b.w;
            }
        }
    }
    #pragma unroll
    for (int j = 0; j < 4; ++j) {
        const int col = tc * 4 + j;
        #pragma unroll
        for (int i = 0; i < 4; ++i) {
            supT[(size_t)col * N_NODES + n0 + tr * 4 + i] =
                (unsigned short)bfr(acc[i][j]);
        }
    }
}

// Kernel 2: partial[h] = adj[:, hK] @ support[hK]  (fp32 partials)
// BM=64, BK=32, split-K=4. 512 blocks x 512 thr (8 waves 2Mx4N, wave=32x32).
// 4 x 16KB LDS buffers, depth-3 prefetch, uniform 2 DMA ops/wave/iter,
// steady s_waitcnt vmcnt(4) -> tiles tt+1,tt+2 stay in flight across barrier.
__global__ __launch_bounds__(512, 4) void gcn_kernel(
        const float* __restrict__ adj, const unsigned short* __restrict__ supT,
        float* __restrict__ part) {
    __shared__ char lds[NBUF * BUFB];       // 64 KB
    const int t = threadIdx.x;
    const int l = t & 63;
    const int w = t >> 6;                   // 0..7
    const int rb = blockIdx.x & 127;
    const int h = blockIdx.x >> 7;          // K-quarter
    const int n0 = rb * 64;
    const int k0 = h * KQ;

    // ---- staging sources (per-lane, pre-swizzled) ----
    // A: wave w stages rows 8w..8w+7; lane l -> row 8w+(l>>3), stored chunk l&7
    //    logical chunk = (l&7) ^ ((l>>3)&7)   [LDS addr(r,c)=r*128+((c^(r&7))*16]
    const int rA = 8 * w + (l >> 3);
    const char* gA = (const char*)adj
        + ((size_t)(n0 + rA) * N_NODES + k0) * 4
        + (((l & 7) ^ ((l >> 3) & 7)) * 16);
    // B: wave w stages f rows 16w..16w+15; lane l -> f=16w+(l>>2), stored chunk l&3
    //    logical chunk = (l&3) ^ ((l>>3)&3)  [addr(f,c)=f*64+((c^((f>>1)&3))*16]
    const int fB = 16 * w + (l >> 2);
    const char* gB = (const char*)supT
        + ((size_t)fB * N_NODES + k0) * 2
        + (((l & 3) ^ ((l >> 3) & 3)) * 16);

    // wave-uniform LDS dest offsets (HW appends lane*16)
    const int a_d = w * 1024;
    const int b_d = ABYTES + w * 1024;

    // ---- read-side offsets ----
    const int wm = w >> 2, wn = w & 3;
    const int aoff0 = (wm * 32 + (l & 15)) * 128;   // A row, +16 below
    const int aoff1 = aoff0 + 16 * 128;
    const int akey = l & 7;                          // (row)&7
    const int boff0 = ABYTES + (wn * 32 + (l & 15)) * 64;
    const int boff1 = boff0 + 16 * 64;
    const int bkey = (l >> 1) & 3;                   // ((f)>>1)&3
    const int j = l >> 4;                            // k-chunk group

    f32x4 acc00 = {0.f,0.f,0.f,0.f}, acc01 = {0.f,0.f,0.f,0.f};
    f32x4 acc10 = {0.f,0.f,0.f,0.f}, acc11 = {0.f,0.f,0.f,0.f};

#define STAGE(BUF) { \
    char* bb = &lds[(BUF) * BUFB]; \
    gload16(gA, bb + a_d); \
    gload16(gB, bb + b_d); \
    gA += 128; gB += 64; }

#define BODY(TT, WAITIMM, DO_STAGE) { \
    asm volatile("s_waitcnt vmcnt(" WAITIMM ")" ::: "memory"); \
    __builtin_amdgcn_sched_barrier(0); \
    __builtin_amdgcn_s_barrier(); \
    __builtin_amdgcn_sched_barrier(0); \
    if (DO_STAGE) STAGE(((TT) + 3) & (NBUF - 1)); \
    const char* buf = &lds[((TT) & (NBUF - 1)) * BUFB]; \
    f32x4 a0lo = *(const f32x4*)(buf + aoff0 + (((2*j    ) ^ akey) * 16)); \
    f32x4 a0hi = *(const f32x4*)(buf + aoff0 + (((2*j + 1) ^ akey) * 16)); \
    f32x4 a1lo = *(const f32x4*)(buf + aoff1 + (((2*j    ) ^ akey) * 16)); \
    f32x4 a1hi = *(const f32x4*)(buf + aoff1 + (((2*j + 1) ^ akey) * 16)); \
    bf16x8 b0 = *(const bf16x8*)(buf + boff0 + ((j ^ bkey) * 16)); \
    bf16x8 b1 = *(const bf16x8*)(buf + boff1 + ((j ^ bkey) * 16)); \
    bf16x8 am0, am1; \
    am0[0] = bfr(a0lo.x); am0[1] = bfr(a0lo.y); \
    am0[2] = bfr(a0lo.z); am0[3] = bfr(a0lo.w); \
    am0[4] = bfr(a0hi.x); am0[5] = bfr(a0hi.y); \
    am0[6] = bfr(a0hi.z); am0[7] = bfr(a0hi.w); \
    am1[0] = bfr(a1lo.x); am1[1] = bfr(a1lo.y); \
    am1[2] = bfr(a1lo.z); am1[3] = bfr(a1lo.w); \
    am1[4] = bfr(a1hi.x); am1[5] = bfr(a1hi.y); \
    am1[6] = bfr(a1hi.z); am1[7] = bfr(a1hi.w); \
    acc00 = __builtin_amdgcn_mfma_f32_16x16x32_bf16(am0, b0, acc00, 0, 0, 0); \
    acc01 = __builtin_amdgcn_mfma_f32_16x16x32_bf16(am0, b1, acc01, 0, 0, 0); \
    acc10 = __builtin_amdgcn_mfma_f32_16x16x32_bf16(am1, b0, acc10, 0, 0, 0); \
    acc11 = __builtin_amdgcn_mfma_f32_16x16x32_bf16(am1, b1, acc11, 0, 0, 0); }

    // prologue: tiles 0,1,2 -> buffers 0,1,2 (2 ops each, ledger order)
    STAGE(0); STAGE(1); STAGE(2);

    // main: tt = 0..NT-4, steady vmcnt(4); stages tile tt+3
    for (int tt = 0; tt < NT - 3; ++tt) {
        BODY(tt, "4", 1);
    }
    // tail: no staging; drain 4 -> 2 -> 0
    BODY(NT - 3, "4", 0);
    BODY(NT - 2, "2", 0);
    BODY(NT - 1, "0", 0);

#undef BODY
#undef STAGE

    // epilogue -> fp32 partial [h][n][f]
    float* p = part + (size_t)h * N_NODES * F_OUT;
    const int col = wn * 32 + (l & 15);
    const int row0 = n0 + wm * 32 + (l >> 4) * 4;
    #pragma unroll
    for (int i = 0; i < 4; ++i) {
        float* o0 = p + (size_t)(row0 + i) * F_OUT + col;
        float* o1 = p + (size_t)(row0 + i + 16) * F_OUT + col;
        o0[0]  = acc00[i];
        o0[16] = acc01[i];
        o1[0]  = acc10[i];
        o1[16] = acc11[i];
    }
}

// Kernel 3: out = p0+p1+p2+p3 + bias
__global__ __launch_bounds__(256) void add_kernel(
        const float* __restrict__ part, const float* __restrict__ bias,
        float* __restrict__ out) {
    const int i = blockIdx.x * 256 + threadIdx.x;   // 0..131071
    const size_t e = (size_t)i * 8;
    const size_t ps = (size_t)N_NODES * F_OUT;
    f32x4 s0 = *(const f32x4*)(part + e);
    f32x4 s1 = *(const f32x4*)(part + e + 4);
    #pragma unroll
    for (int h = 1; h < SPLITK; ++h) {
        s0 += *(const f32x4*)(part + h * ps + e);
        s1 += *(const f32x4*)(part + h * ps + e + 4);
    }
    const int fb = (i & 15) * 8;                    // (i*8) % 128
    s0 += *(const f32x4*)(bias + fb);
    s1 += *(const f32x4*)(bias + fb + 4);
    *(f32x4*)(out + e)     = s0;
    *(f32x4*)(out + e + 4) = s1;
}

extern "C" void kernel_launch(void* const* d_in, const int* in_sizes, int n_in,
                              void* d_out, int out_size, void* d_ws, size_t ws_size,
                              hipStream_t stream) {
    const float* input  = (const float*)d_in[0];
    const float* adj    = (const float*)d_in[1];
    const float* weight = (const float*)d_in[2];
    const float* bias   = (const float*)d_in[3];
    float* out = (float*)d_out;
    unsigned short* supT = (unsigned short*)d_ws;           // 2 MiB
    float* part = (float*)((char*)d_ws + (4u << 20));       // 4 x 4 MiB

    support_kernel<<<N_NODES / 32, 256, 0, stream>>>(input, weight, supT);
    gcn_kernel<<<128 * SPLITK, 512, 0, stream>>>(adj, supT, part);
    add_kernel<<<(N_NODES * F_OUT) / (256 * 8), 256, 0, stream>>>(part, bias, out);
}

// Round 8
// 87.227 us; speedup vs baseline: 1.1436x; 1.1436x over previous
//
#include <hip/hip_runtime.h>
#include <hip/hip_bf16.h>

#define N_NODES 8192
#define F_IN 256
#define F_OUT 128

#define SPLITK 4
#define KQ (N_NODES / SPLITK)   // 2048
#define BK 64
#define NT (KQ / BK)            // 32
#define ABYTES 16384            // A tile: 64 rows x 64 k x fp32
#define BBYTES 16384            // B tile: 128 f x 64 k x bf16
#define LDS_TOTAL (3 * ABYTES + 2 * BBYTES)   // 80 KB

typedef __attribute__((ext_vector_type(4))) float f32x4;
typedef __attribute__((ext_vector_type(8))) short bf16x8;

static __device__ __forceinline__ short bfr(float x) {
    __hip_bfloat16 h = __float2bfloat16(x);   // RNE
    union { __hip_bfloat16 h; short s; } u; u.h = h;
    return u.s;
}

static __device__ __forceinline__ void gload16(const void* g, void* l) {
    __builtin_amdgcn_global_load_lds(
        (const __attribute__((address_space(1))) unsigned int*)g,
        (__attribute__((address_space(3))) unsigned int*)l, 16, 0, 0);
}

// Kernel 1: support^T[f][n] = sum_k X[n][k] * W[k][f]   (fp32 accum -> bf16)
__global__ __launch_bounds__(256) void support_kernel(
        const float* __restrict__ X, const float* __restrict__ W,
        unsigned short* __restrict__ supT) {
    __shared__ float Xs[32][68];
    __shared__ float Ws[64][128];
    const int t = threadIdx.x;
    const int n0 = blockIdx.x * 32;
    const int tc = t & 31;
    const int tr = t >> 5;
    float acc[4][4];
    #pragma unroll
    for (int i = 0; i < 4; ++i)
        #pragma unroll
        for (int j = 0; j < 4; ++j) acc[i][j] = 0.f;

    for (int k0 = 0; k0 < F_IN; k0 += 64) {
        __syncthreads();
        {
            const int r = t >> 3, kc = (t & 7) * 8;
            const float* src = X + (size_t)(n0 + r) * F_IN + k0 + kc;
            f32x4 v0 = *(const f32x4*)src;
            f32x4 v1 = *(const f32x4*)(src + 4);
            *(f32x4*)&Xs[r][kc]     = v0;
            *(f32x4*)&Xs[r][kc + 4] = v1;
        }
        {
            const int col = t & 127, kb = t >> 7;
            #pragma unroll
            for (int i = 0; i < 32; ++i) {
                const int k = kb + i * 2;
                Ws[k][col] = W[(size_t)(k0 + k) * F_OUT + col];
            }
        }
        __syncthreads();
        #pragma unroll 8
        for (int k = 0; k < 64; ++k) {
            const f32x4 b = *(const f32x4*)&Ws[k][tc * 4];
            float a[4];
            #pragma unroll
            for (int i = 0; i < 4; ++i) a[i] = Xs[tr * 4 + i][k];
            #pragma unroll
            for (int i = 0; i < 4; ++i) {
                acc[i][0] += a[i] * b.x; acc[i][1] += a[i] * b.y;
                acc[i][2] += a[i] * b.z; acc[i][3] += a[i] * b.w;
            }
        }
    }
    #pragma unroll
    for (int j = 0; j < 4; ++j) {
        const int col = tc * 4 + j;
        #pragma unroll
        for (int i = 0; i < 4; ++i) {
            supT[(size_t)col * N_NODES + n0 + tr * 4 + i] =
                (unsigned short)bfr(acc[i][j]);
        }
    }
}

// Kernel 2: partial[h] = adj[:, hK] @ support[hK]  (fp32 partials)
// BM=64, BK=64, split-K=4. 512 blocks x 512 thr (8 waves 2Mx4N, wave=32x32).
// Asymmetric-depth pipeline: A (HBM) triple-buffered depth-2, B (L2)
// double-buffered depth-1. Per-iter issue order [B(tt+1), A(tt+2)] makes the
// FIFO at each iter top = [A(tt), B(tt), A(tt+1)] -> uniform vmcnt(2) retires
// tile tt while A(tt+1) stays in flight across the single barrier.
__global__ __launch_bounds__(512, 4) void gcn_kernel(
        const float* __restrict__ adj, const unsigned short* __restrict__ supT,
        float* __restrict__ part) {
    extern __shared__ char lds[];           // 80 KB: A x3 @0, B x2 @48K
    const int t = threadIdx.x;
    const int l = t & 63;
    const int w = t >> 6;                   // 0..7
    const int rb = blockIdx.x & 127;
    const int h = blockIdx.x >> 7;          // K-quarter
    const int n0 = rb * 64;
    const int k0 = h * KQ;

    // ---- staging sources (per-lane, pre-swizzled; R6-proven) ----
    const int rA0 = 8 * w + (l >> 4);
    const int rA1 = rA0 + 4;
    const char* gA0 = (const char*)adj
        + ((size_t)(n0 + rA0) * N_NODES + k0) * 4 + (((l & 15) ^ (rA0 & 15)) * 16);
    const char* gA1 = (const char*)adj
        + ((size_t)(n0 + rA1) * N_NODES + k0) * 4 + (((l & 15) ^ (rA1 & 15)) * 16);
    const char* gB0 = (const char*)supT
        + ((size_t)(16 * w + (l >> 3)) * N_NODES + k0) * 2 + (((l & 7) ^ (l >> 3)) * 16);
    const char* gB1 = gB0 + (size_t)8 * N_NODES * 2;

    // wave-uniform LDS dest offsets within a region (HW appends lane*16)
    const int a_d0 = w * 2048;
    const int a_d1 = a_d0 + 1024;
    const int b_d0 = w * 2048;
    const int b_d1 = b_d0 + 1024;

    // ---- read-side offsets (region-relative) ----
    const int wm = w >> 2, wn = w & 3;
    const int aoff0 = (wm * 32 + (l & 15)) * 256;
    const int aoff1 = aoff0 + 16 * 256;
    const int akey = l & 15;
    const int ac0 = (l >> 4) * 2;
    const int boff0 = (wn * 32 + (l & 15)) * 128;
    const int boff1 = boff0 + 16 * 128;
    const int bkey = l & 7;
    const int cb0 = l >> 4;

    f32x4 acc00 = {0.f,0.f,0.f,0.f}, acc01 = {0.f,0.f,0.f,0.f};
    f32x4 acc10 = {0.f,0.f,0.f,0.f}, acc11 = {0.f,0.f,0.f,0.f};

#define STAGE_A(OFF) { \
    char* bb = &lds[OFF]; \
    gload16(gA0, bb + a_d0); \
    gload16(gA1, bb + a_d1); \
    gA0 += 256; gA1 += 256; }

#define STAGE_B(OFF) { \
    char* bb = &lds[3 * ABYTES + (OFF)]; \
    gload16(gB0, bb + b_d0); \
    gload16(gB1, bb + b_d1); \
    gB0 += 128; gB1 += 128; }

    // prologue (FIFO order matters): B(0), A(0), A(1)
    STAGE_B(0);
    STAGE_A(0);
    STAGE_A(ABYTES);

    int ai = 0;                  // tt % 3
    int bi = 0;                  // tt & 1
    for (int tt = 0; tt < NT; ++tt) {
        if (tt < NT - 1) asm volatile("s_waitcnt vmcnt(2)" ::: "memory");
        else             asm volatile("s_waitcnt vmcnt(0)" ::: "memory");
        __builtin_amdgcn_sched_barrier(0);
        __builtin_amdgcn_s_barrier();
        __builtin_amdgcn_sched_barrier(0);

        // issue next tiles: B(tt+1) first, then A(tt+2)  (FIFO discipline)
        if (tt < NT - 1) STAGE_B((bi ^ 1) * BBYTES);
        if (tt < NT - 2) { const int as = ai ? ai - 1 : 2; STAGE_A(as * ABYTES); }

        const char* abuf = &lds[ai * ABYTES];
        const char* bbuf = &lds[3 * ABYTES + bi * BBYTES];
        #pragma unroll
        for (int ks = 0; ks < 2; ++ks) {
            const int ca = ks * 8 + ac0;
            f32x4 a0lo = *(const f32x4*)(abuf + aoff0 + (((ca    ) ^ akey) * 16));
            f32x4 a0hi = *(const f32x4*)(abuf + aoff0 + (((ca + 1) ^ akey) * 16));
            f32x4 a1lo = *(const f32x4*)(abuf + aoff1 + (((ca    ) ^ akey) * 16));
            f32x4 a1hi = *(const f32x4*)(abuf + aoff1 + (((ca + 1) ^ akey) * 16));
            const int cb = ks * 4 + cb0;
            bf16x8 b0 = *(const bf16x8*)(bbuf + boff0 + ((cb ^ bkey) * 16));
            bf16x8 b1 = *(const bf16x8*)(bbuf + boff1 + ((cb ^ bkey) * 16));
            bf16x8 am0, am1;
            am0[0] = bfr(a0lo.x); am0[1] = bfr(a0lo.y);
            am0[2] = bfr(a0lo.z); am0[3] = bfr(a0lo.w);
            am0[4] = bfr(a0hi.x); am0[5] = bfr(a0hi.y);
            am0[6] = bfr(a0hi.z); am0[7] = bfr(a0hi.w);
            am1[0] = bfr(a1lo.x); am1[1] = bfr(a1lo.y);
            am1[2] = bfr(a1lo.z); am1[3] = bfr(a1lo.w);
            am1[4] = bfr(a1hi.x); am1[5] = bfr(a1hi.y);
            am1[6] = bfr(a1hi.z); am1[7] = bfr(a1hi.w);
            acc00 = __builtin_amdgcn_mfma_f32_16x16x32_bf16(am0, b0, acc00, 0, 0, 0);
            acc01 = __builtin_amdgcn_mfma_f32_16x16x32_bf16(am0, b1, acc01, 0, 0, 0);
            acc10 = __builtin_amdgcn_mfma_f32_16x16x32_bf16(am1, b0, acc10, 0, 0, 0);
            acc11 = __builtin_amdgcn_mfma_f32_16x16x32_bf16(am1, b1, acc11, 0, 0, 0);
        }
        ai = (ai == 2) ? 0 : ai + 1;
        bi ^= 1;
    }
#undef STAGE_A
#undef STAGE_B

    // epilogue -> fp32 partial [h][n][f]
    float* p = part + (size_t)h * N_NODES * F_OUT;
    const int col = wn * 32 + (l & 15);
    const int row0 = n0 + wm * 32 + (l >> 4) * 4;
    #pragma unroll
    for (int i = 0; i < 4; ++i) {
        float* o0 = p + (size_t)(row0 + i) * F_OUT + col;
        float* o1 = p + (size_t)(row0 + i + 16) * F_OUT + col;
        o0[0]  = acc00[i];
        o0[16] = acc01[i];
        o1[0]  = acc10[i];
        o1[16] = acc11[i];
    }
}

// Kernel 3: out = p0+p1+p2+p3 + bias
__global__ __launch_bounds__(256) void add_kernel(
        const float* __restrict__ part, const float* __restrict__ bias,
        float* __restrict__ out) {
    const int i = blockIdx.x * 256 + threadIdx.x;   // 0..131071
    const size_t e = (size_t)i * 8;
    const size_t ps = (size_t)N_NODES * F_OUT;
    f32x4 s0 = *(const f32x4*)(part + e);
    f32x4 s1 = *(const f32x4*)(part + e + 4);
    #pragma unroll
    for (int h = 1; h < SPLITK; ++h) {
        s0 += *(const f32x4*)(part + h * ps + e);
        s1 += *(const f32x4*)(part + h * ps + e + 4);
    }
    const int fb = (i & 15) * 8;                    // (i*8) % 128
    s0 += *(const f32x4*)(bias + fb);
    s1 += *(const f32x4*)(bias + fb + 4);
    *(f32x4*)(out + e)     = s0;
    *(f32x4*)(out + e + 4) = s1;
}

extern "C" void kernel_launch(void* const* d_in, const int* in_sizes, int n_in,
                              void* d_out, int out_size, void* d_ws, size_t ws_size,
                              hipStream_t stream) {
    const float* input  = (const float*)d_in[0];
    const float* adj    = (const float*)d_in[1];
    const float* weight = (const float*)d_in[2];
    const float* bias   = (const float*)d_in[3];
    float* out = (float*)d_out;
    unsigned short* supT = (unsigned short*)d_ws;           // 2 MiB
    float* part = (float*)((char*)d_ws + (4u << 20));       // 4 x 4 MiB

    // opt-in for 80 KB dynamic LDS (attribute set, not a stream op;
    // graph-capture safe; idempotent)
    (void)hipFuncSetAttribute((const void*)gcn_kernel,
                              hipFuncAttributeMaxDynamicSharedMemorySize,
                              LDS_TOTAL);

    support_kernel<<<N_NODES / 32, 256, 0, stream>>>(input, weight, supT);
    gcn_kernel<<<128 * SPLITK, 512, LDS_TOTAL, stream>>>(adj, supT, part);
    add_kernel<<<(N_NODES * F_OUT) / (256 * 8), 256, 0, stream>>>(part, bias, out);
}

// Round 9
// 77.733 us; speedup vs baseline: 1.2832x; 1.1221x over previous
//
#include <hip/hip_runtime.h>
#include <hip/hip_bf16.h>

#define N_NODES 8192
#define F_IN 256
#define F_OUT 128

#define SPLITK 4
#define KQ (N_NODES / SPLITK)   // 2048
#define BK 64
#define NT (KQ / BK)            // 32
#define ABYTES 16384            // A tile: 64 rows x 64 k x fp32
#define BBYTES 16384            // B tile: 128 f x 64 k x bf16
#define BUFB (ABYTES + BBYTES)  // 32 KB

typedef __attribute__((ext_vector_type(4))) float f32x4;
typedef __attribute__((ext_vector_type(8))) short bf16x8;
typedef __attribute__((ext_vector_type(4))) unsigned int u32x4;

static __device__ __forceinline__ short bfr(float x) {
    __hip_bfloat16 h = __float2bfloat16(x);   // RNE
    union { __hip_bfloat16 h; short s; } u; u.h = h;
    return u.s;
}

static __device__ __forceinline__ void gload16(const void* g, void* l) {
    __builtin_amdgcn_global_load_lds(
        (const __attribute__((address_space(1))) unsigned int*)g,
        (__attribute__((address_space(3))) unsigned int*)l, 16, 0, 0);
}

// Kernel 1: support^T[f][n] = sum_k X[n][k] * W[k][f]   (fp32 accum -> bf16)
__global__ __launch_bounds__(256) void support_kernel(
        const float* __restrict__ X, const float* __restrict__ W,
        unsigned short* __restrict__ supT) {
    __shared__ float Xs[32][68];
    __shared__ float Ws[64][128];
    const int t = threadIdx.x;
    const int n0 = blockIdx.x * 32;
    const int tc = t & 31;
    const int tr = t >> 5;
    float acc[4][4];
    #pragma unroll
    for (int i = 0; i < 4; ++i)
        #pragma unroll
        for (int j = 0; j < 4; ++j) acc[i][j] = 0.f;

    for (int k0 = 0; k0 < F_IN; k0 += 64) {
        __syncthreads();
        {
            const int r = t >> 3, kc = (t & 7) * 8;
            const float* src = X + (size_t)(n0 + r) * F_IN + k0 + kc;
            f32x4 v0 = *(const f32x4*)src;
            f32x4 v1 = *(const f32x4*)(src + 4);
            *(f32x4*)&Xs[r][kc]     = v0;
            *(f32x4*)&Xs[r][kc + 4] = v1;
        }
        {
            const int col = t & 127, kb = t >> 7;
            #pragma unroll
            for (int i = 0; i < 32; ++i) {
                const int k = kb + i * 2;
                Ws[k][col] = W[(size_t)(k0 + k) * F_OUT + col];
            }
        }
        __syncthreads();
        #pragma unroll 8
        for (int k = 0; k < 64; ++k) {
            const f32x4 b = *(const f32x4*)&Ws[k][tc * 4];
            float a[4];
            #pragma unroll
            for (int i = 0; i < 4; ++i) a[i] = Xs[tr * 4 + i][k];
            #pragma unroll
            for (int i = 0; i < 4; ++i) {
                acc[i][0] += a[i] * b.x; acc[i][1] += a[i] * b.y;
                acc[i][2] += a[i] * b.z; acc[i][3] += a[i] * b.w;
            }
        }
    }
    #pragma unroll
    for (int j = 0; j < 4; ++j) {
        const int col = tc * 4 + j;
        #pragma unroll
        for (int i = 0; i < 4; ++i) {
            supT[(size_t)col * N_NODES + n0 + tr * 4 + i] =
                (unsigned short)bfr(acc[i][j]);
        }
    }
}

// Kernel 2: out += adj[:, hK] @ support[hK]  (+bias when h==0), via HW fp32
// atomics onto zeroed out. BM=64, BK=64, split-K=4. 512 blocks x 512 thr
// (8 waves 2Mx4N, wave=32x32). R6-proven T3-minimum 2-phase:
// STAGE(next) -> compute(cur) -> vmcnt(0) -> raw s_barrier. 2 blocks/CU.
// A-fragment fp32->bf16 via v_cvt_pk_bf16_f32 (1 VALU op per 2 elements).
__global__ __launch_bounds__(512, 4) void gcn_kernel(
        const float* __restrict__ adj, const unsigned short* __restrict__ supT,
        const float* __restrict__ bias, float* __restrict__ out) {
    __shared__ char lds[2 * BUFB];          // 64 KB
    const int t = threadIdx.x;
    const int l = t & 63;
    const int w = t >> 6;                   // 0..7
    const int rb = blockIdx.x & 127;
    const int h = blockIdx.x >> 7;          // K-quarter
    const int n0 = rb * 64;
    const int k0 = h * KQ;

    // ---- staging sources (per-lane, pre-swizzled; R6-proven) ----
    const int rA0 = 8 * w + (l >> 4);
    const int rA1 = rA0 + 4;
    const char* gA0 = (const char*)adj
        + ((size_t)(n0 + rA0) * N_NODES + k0) * 4 + (((l & 15) ^ (rA0 & 15)) * 16);
    const char* gA1 = (const char*)adj
        + ((size_t)(n0 + rA1) * N_NODES + k0) * 4 + (((l & 15) ^ (rA1 & 15)) * 16);
    const char* gB0 = (const char*)supT
        + ((size_t)(16 * w + (l >> 3)) * N_NODES + k0) * 2 + (((l & 7) ^ (l >> 3)) * 16);
    const char* gB1 = gB0 + (size_t)8 * N_NODES * 2;

    // wave-uniform LDS dest offsets (HW appends lane*16)
    const int a_d0 = w * 2048;
    const int a_d1 = a_d0 + 1024;
    const int b_d0 = ABYTES + w * 2048;
    const int b_d1 = b_d0 + 1024;

    // ---- read-side offsets ----
    const int wm = w >> 2, wn = w & 3;
    const int aoff0 = (wm * 32 + (l & 15)) * 256;
    const int aoff1 = aoff0 + 16 * 256;
    const int akey = l & 15;
    const int ac0 = (l >> 4) * 2;
    const int boff0 = ABYTES + (wn * 32 + (l & 15)) * 128;
    const int boff1 = boff0 + 16 * 128;
    const int bkey = l & 7;
    const int cb0 = l >> 4;

    f32x4 acc00 = {0.f,0.f,0.f,0.f}, acc01 = {0.f,0.f,0.f,0.f};
    f32x4 acc10 = {0.f,0.f,0.f,0.f}, acc11 = {0.f,0.f,0.f,0.f};

#define PK(dst, a, b) \
    asm("v_cvt_pk_bf16_f32 %0, %1, %2" : "=v"(dst) : "v"(a), "v"(b))

#define STAGE(BUF) { \
    char* bb = &lds[(BUF) * BUFB]; \
    gload16(gA0, bb + a_d0); \
    gload16(gA1, bb + a_d1); \
    gload16(gB0, bb + b_d0); \
    gload16(gB1, bb + b_d1); \
    gA0 += 256; gA1 += 256; gB0 += 128; gB1 += 128; }

#define FENCE_BARRIER() { \
    asm volatile("s_waitcnt vmcnt(0)" ::: "memory"); \
    __builtin_amdgcn_sched_barrier(0); \
    __builtin_amdgcn_s_barrier(); \
    __builtin_amdgcn_sched_barrier(0); }

    // prologue: tile 0 -> buffer 0
    STAGE(0);
    FENCE_BARRIER();

    for (int tt = 0; tt < NT; ++tt) {
        if (tt + 1 < NT) STAGE((tt + 1) & 1);

        const char* buf = &lds[(tt & 1) * BUFB];
        #pragma unroll
        for (int ks = 0; ks < 2; ++ks) {
            const int ca = ks * 8 + ac0;
            f32x4 a0lo = *(const f32x4*)(buf + aoff0 + (((ca    ) ^ akey) * 16));
            f32x4 a0hi = *(const f32x4*)(buf + aoff0 + (((ca + 1) ^ akey) * 16));
            f32x4 a1lo = *(const f32x4*)(buf + aoff1 + (((ca    ) ^ akey) * 16));
            f32x4 a1hi = *(const f32x4*)(buf + aoff1 + (((ca + 1) ^ akey) * 16));
            const int cb = ks * 4 + cb0;
            bf16x8 b0 = *(const bf16x8*)(buf + boff0 + ((cb ^ bkey) * 16));
            bf16x8 b1 = *(const bf16x8*)(buf + boff1 + ((cb ^ bkey) * 16));
            u32x4 p0, p1;
            PK(p0.x, a0lo.x, a0lo.y); PK(p0.y, a0lo.z, a0lo.w);
            PK(p0.z, a0hi.x, a0hi.y); PK(p0.w, a0hi.z, a0hi.w);
            PK(p1.x, a1lo.x, a1lo.y); PK(p1.y, a1lo.z, a1lo.w);
            PK(p1.z, a1hi.x, a1hi.y); PK(p1.w, a1hi.z, a1hi.w);
            bf16x8 am0 = __builtin_bit_cast(bf16x8, p0);
            bf16x8 am1 = __builtin_bit_cast(bf16x8, p1);
            acc00 = __builtin_amdgcn_mfma_f32_16x16x32_bf16(am0, b0, acc00, 0, 0, 0);
            acc01 = __builtin_amdgcn_mfma_f32_16x16x32_bf16(am0, b1, acc01, 0, 0, 0);
            acc10 = __builtin_amdgcn_mfma_f32_16x16x32_bf16(am1, b0, acc10, 0, 0, 0);
            acc11 = __builtin_amdgcn_mfma_f32_16x16x32_bf16(am1, b1, acc11, 0, 0, 0);
        }
        FENCE_BARRIER();
    }
#undef STAGE
#undef FENCE_BARRIER
#undef PK

    // epilogue: atomic-accumulate into out (zeroed by host-side memset);
    // h==0 contributes the bias exactly once per output element.
    const int col = wn * 32 + (l & 15);
    const int row0 = n0 + wm * 32 + (l >> 4) * 4;
    const float bv0 = (h == 0) ? bias[col]      : 0.0f;
    const float bv1 = (h == 0) ? bias[col + 16] : 0.0f;
    #pragma unroll
    for (int i = 0; i < 4; ++i) {
        float* o0 = out + (size_t)(row0 + i) * F_OUT + col;
        float* o1 = out + (size_t)(row0 + i + 16) * F_OUT + col;
        unsafeAtomicAdd(&o0[0],  acc00[i] + bv0);
        unsafeAtomicAdd(&o0[16], acc01[i] + bv1);
        unsafeAtomicAdd(&o1[0],  acc10[i] + bv0);
        unsafeAtomicAdd(&o1[16], acc11[i] + bv1);
    }
}

extern "C" void kernel_launch(void* const* d_in, const int* in_sizes, int n_in,
                              void* d_out, int out_size, void* d_ws, size_t ws_size,
                              hipStream_t stream) {
    const float* input  = (const float*)d_in[0];
    const float* adj    = (const float*)d_in[1];
    const float* weight = (const float*)d_in[2];
    const float* bias   = (const float*)d_in[3];
    float* out = (float*)d_out;
    unsigned short* supT = (unsigned short*)d_ws;           // 2 MiB

    // zero the output accumulator (memset node is graph-capturable)
    hipMemsetAsync(d_out, 0, (size_t)out_size * sizeof(float), stream);

    support_kernel<<<N_NODES / 32, 256, 0, stream>>>(input, weight, supT);
    gcn_kernel<<<128 * SPLITK, 512, 0, stream>>>(adj, supT, bias, out);
}